// Round 5
// baseline (807.869 us; speedup 1.0000x reference)
//
#include <hip/hip_runtime.h>
#include <cstdint>
#include <cstddef>

#define D_MODEL 1024
#define SEQ 8192

typedef __bf16  bf16x8 __attribute__((ext_vector_type(8)));
typedef short   short8 __attribute__((ext_vector_type(8)));
typedef float   f32x4  __attribute__((ext_vector_type(4)));
typedef unsigned short ushort_t;

__device__ __forceinline__ ushort_t f2bf(float f) {
  uint32_t u = __builtin_bit_cast(uint32_t, f);
  u += 0x7FFFu + ((u >> 16) & 1u);          // round-to-nearest-even
  return (ushort_t)(u >> 16);
}
// async global->LDS, 16B per lane. LDS dest is wave-uniform base + lane*16.
__device__ __forceinline__ void gll16(const void* g, void* l) {
  __builtin_amdgcn_global_load_lds(
      (const __attribute__((address_space(1))) void*)g,
      (__attribute__((address_space(3))) void*)l, 16, 0, 0);
}
// stage one 128x64 bf16 half-tile (16 KB): 2 gll16 per lane, 8 waves cover 128 rows.
__device__ __forceinline__ void stage_half(const ushort_t* g, char* l0) {
  gll16(g, l0);                       // rows  0..63 of half
  gll16(g + 65536, l0 + 8192);        // rows 64..127 of half (+64*1024 elems)
}

// ---------------- fp32 -> bf16 conversion of x ----------------
__global__ void k_convert_x(const float* __restrict__ x, ushort_t* __restrict__ xb, int n) {
  int i = (blockIdx.x * 256 + threadIdx.x) * 8;
  if (i >= n) return;
  float4 v0 = *(const float4*)(x + i);
  float4 v1 = *(const float4*)(x + i + 4);
  ushort_t o[8] = { f2bf(v0.x), f2bf(v0.y), f2bf(v0.z), f2bf(v0.w),
                    f2bf(v1.x), f2bf(v1.y), f2bf(v1.z), f2bf(v1.w) };
  *(short8*)(xb + i) = *(const short8*)o;
}

// ---------------- W (k,n) fp32 -> Wt (n,k) bf16; z<3 -> fused qkv buffer ----------------
__global__ void k_transpose_w(const float* W0, const float* W1, const float* W2, const float* W3,
                              ushort_t* Tqkv, ushort_t* To) {
  const float* src; ushort_t* dst;
  switch (blockIdx.z) {
    case 0: src = W0; dst = Tqkv; break;
    case 1: src = W1; dst = Tqkv + (size_t)1024 * 1024; break;
    case 2: src = W2; dst = Tqkv + (size_t)2048 * 1024; break;
    default: src = W3; dst = To; break;
  }
  __shared__ float tile[64][65];
  int tx = threadIdx.x;
  int c = tx & 63, r0 = tx >> 6;
  int bx = blockIdx.x * 64, by = blockIdx.y * 64;
  #pragma unroll
  for (int i = 0; i < 16; i++) {
    int r = i * 4 + r0;
    tile[r][c] = src[(size_t)(by + r) * D_MODEL + bx + c];
  }
  __syncthreads();
  #pragma unroll
  for (int i = 0; i < 16; i++) {
    int r = i * 4 + r0;
    dst[(size_t)(bx + r) * D_MODEL + by + c] = f2bf(tile[c][r]);
  }
}

// ---------------- 256x256-tile bf16 GEMM: one-half-read-per-phase pipeline ----------------
// C = A(M,K) * Bt(N,K)^T + bias. BK=64, 8 waves (2Mx4N), LDS 128KB dbuf, 1 block/CU.
// Per K-tile T, 4 phases; per phase: {one half-tile ds_read burst (8 A / 4 B),
// stage gll16s, barrier, counted LGW (own reads stay in flight), setprio+16 MFMA,
// [vmcnt(0) at P1 only], barrier}. Every MFMA operand was ds_read 1-2 phases
// earlier -> LGW covers reads with a full phase to drain -> LDS pipe overlaps MFMA.
//   P0: read a1=A1(T)[bufT];  stage B_hi(T+1)->bufN;        MFMA Q00(a0,b0)
//   P1: read b1=B1(T)[bufT];                                MFMA Q10(a1,b0); vmcnt(0)
//   P2: read b0=B0(T+1)[bufN]; stage A_lo(T+2)->bufT;       MFMA Q01(a0,b1)
//   P3: read a0=A0(T+1)[bufN]; stage A_hi,B_lo(T+2)->bufT;  MFMA Q11(a1,b1)
// WAR ledger: every staged region's last reads drain at an LGW >=1 barrier before
// the stage. vmcnt(0)@P1 drains tile T+1 (all 8 stage-ops since previous P1 are
// exactly T+1's four halves) before its reads at P2/P3/next-P0/next-P1.
// Stagers: S2 (tile T stages T+2) must run for T=0..13  [R4 bug: tile13 skipped
// -> tile15 read stale; fixed], S1 (B_hi(T+1)) for T=0..14.
// T1 bijective XCD swizzle, T2 chunk-XOR swizzle, T5 setprio.
// MODE 0: fused QKV (N=3072): region 0/1 -> elu+1 -> o0/o1; region 2 -> o2. bf16 out.
// MODE 2: fp32 out (+bias), single output.
template<int MODE, int NY>
__global__ __launch_bounds__(512, 2) void k_gemm(const ushort_t* __restrict__ A,
                                                 const ushort_t* __restrict__ Bt,
                                                 const float* __restrict__ b0,
                                                 const float* __restrict__ b1,
                                                 const float* __restrict__ b2,
                                                 ushort_t* __restrict__ o0,
                                                 ushort_t* __restrict__ o1,
                                                 ushort_t* __restrict__ o2,
                                                 float* __restrict__ outf) {
  __shared__ __align__(16) char smem[131072];   // 2 x (A 32KB + B 32KB) dbuf; epilogue reuses

  const int nwg = gridDim.x;
  const int bid0 = blockIdx.x;
  const int bid = (bid0 & 7) * (nwg >> 3) + (bid0 >> 3);   // XCD-aware, bijective (nwg%8==0)
  const int xb = bid / NY, yb = bid % NY;                  // N-fastest: A-panel L2 reuse
  const int m0 = xb * 256, n0 = yb * 256;

  const int tid = threadIdx.x;
  const int ln = tid & 63;
  const int w  = tid >> 6;
  const int wb = __builtin_amdgcn_readfirstlane(w);
  const int wm = wb >> 2, wn = wb & 3;          // 2x4 wave grid; per-wave C = 128x64

  // --- staging: thread's (row,chunk) slot; global chunk pre-swizzled (c ^= row&7) ---
  const int srow = wb * 8 + (ln >> 3);                       // row in half-tile
  const int schk = ((ln & 7) ^ ((ln >> 3) & 7)) * 8;         // swizzled source chunk (elems)
  const ushort_t* gA = A  + (size_t)(m0 + srow) * D_MODEL + schk;
  const ushort_t* gB = Bt + (size_t)(n0 + srow) * D_MODEL + schk;

#define STG_A(BASE, H, T) stage_half(gA + (size_t)(T) * 64 + (size_t)(H) * 131072, smem + (BASE) + (H) * 16384 + wb * 1024)
#define STG_B(BASE, H, T) stage_half(gB + (size_t)(T) * 64 + (size_t)(H) * 131072, smem + (BASE) + 32768 + (H) * 16384 + wb * 1024)

#define VMW_(N) asm volatile("s_waitcnt vmcnt(" #N ")" ::: "memory")
#define VMW(N)  VMW_(N)
#define LGW_(N) asm volatile("s_waitcnt lgkmcnt(" #N ")" ::: "memory")
#define LGW__(N) LGW_(N)
#define LGW(N)  do { LGW__(N); __builtin_amdgcn_sched_barrier(0); } while (0)
#define BARSB { __builtin_amdgcn_s_barrier(); __builtin_amdgcn_sched_barrier(0); }

  f32x4 acc[8][4];
  #pragma unroll
  for (int i = 0; i < 8; i++)
    #pragma unroll
    for (int j = 0; j < 4; j++) acc[i][j] = (f32x4){0.f, 0.f, 0.f, 0.f};
  bf16x8 a0f[4][2], a1f[4][2];      // A half frags: 4 mi x 2 ksub each (32 VGPR each)
  bf16x8 b0f[2][2], b1f[2][2];      // B half frags: 2 nj x 2 ksub each (16 VGPR each)

  const int ar  = ln & 15;
  const int cw0 = (((ln >> 4)    ) ^ (ln & 7)) << 4;         // swizzled 16B chunk offs, ksub0
  const int cw1 = (((ln >> 4) + 4) ^ (ln & 7)) << 4;         // ksub1

// A-half MH (64 rows: wm*128 + MH*64): 8 ds_read_b128
#define LDAH(DST, BASE, MH) { _Pragma("unroll") for (int m_ = 0; m_ < 4; ++m_) { \
    const char* p_ = smem + (BASE) + ((wm * 128 + (MH) * 64 + m_ * 16 + ar) << 7); \
    DST[m_][0] = *(const bf16x8*)(p_ + cw0); DST[m_][1] = *(const bf16x8*)(p_ + cw1); } }
// B-half NH (32 cols: wn*64 + NH*32): 4 ds_read_b128
#define LDBH(DST, BASE, NH) { _Pragma("unroll") for (int j_ = 0; j_ < 2; ++j_) { \
    const char* p_ = smem + (BASE) + 32768 + ((wn * 64 + (NH) * 32 + j_ * 16 + ar) << 7); \
    DST[j_][0] = *(const bf16x8*)(p_ + cw0); DST[j_][1] = *(const bf16x8*)(p_ + cw1); } }
// quadrant (MH,NH): 16 MFMA into acc[MH*4+mi][NH*2+nj]
#define QUAD(MH, NH, AF, BF) { _Pragma("unroll") for (int m_ = 0; m_ < 4; ++m_) \
    _Pragma("unroll") for (int j_ = 0; j_ < 2; ++j_) { \
      acc[(MH)*4+m_][(NH)*2+j_] = __builtin_amdgcn_mfma_f32_16x16x32_bf16(AF[m_][0], BF[j_][0], acc[(MH)*4+m_][(NH)*2+j_], 0, 0, 0); \
      acc[(MH)*4+m_][(NH)*2+j_] = __builtin_amdgcn_mfma_f32_16x16x32_bf16(AF[m_][1], BF[j_][1], acc[(MH)*4+m_][(NH)*2+j_], 0, 0, 0); } }

  // One K-tile. BT/BN: LDS byte bases of buf(T parity)/buf(T+1 parity).
  // S1: stage B_hi(T+1) at P0 (T<=14). S2: stage tile T+2 at P2/P3 (T<=13).
  // R1: read tile T+1 at P2/P3 (T<=14). LP2/LP3: LGW at P2/P3 (steady 4/8; T15 0/0).
#define TILE(T, BT, BN, S1, S2, R1, LP2, LP3) { \
    /* P0 */ \
    LDAH(a1f, BT, 1); \
    if (S1) STG_B(BN, 1, (T) + 1); \
    BARSB; \
    LGW(8); \
    __builtin_amdgcn_s_setprio(1); QUAD(0, 0, a0f, b0f); __builtin_amdgcn_s_setprio(0); \
    BARSB; \
    /* P1 */ \
    LDBH(b1f, BT, 1); \
    BARSB; \
    LGW(4); \
    __builtin_amdgcn_s_setprio(1); QUAD(1, 0, a1f, b0f); __builtin_amdgcn_s_setprio(0); \
    VMW(0); \
    BARSB; \
    /* P2 */ \
    if (R1) LDBH(b0f, BN, 0); \
    if (S2) STG_A(BT, 0, (T) + 2); \
    BARSB; \
    LGW(LP2); \
    __builtin_amdgcn_s_setprio(1); QUAD(0, 1, a0f, b1f); __builtin_amdgcn_s_setprio(0); \
    BARSB; \
    /* P3 */ \
    if (R1) LDAH(a0f, BN, 0); \
    if (S2) { STG_A(BT, 1, (T) + 2); STG_B(BT, 0, (T) + 2); } \
    BARSB; \
    LGW(LP3); \
    __builtin_amdgcn_s_setprio(1); QUAD(1, 1, a1f, b1f); __builtin_amdgcn_s_setprio(0); \
    BARSB; \
  }

  // prologue: tile0 (4 halves) + tile1 {A_lo, A_hi, B_lo}; B_hi(1) staged at P0(0).
  STG_A(0, 0, 0); STG_A(0, 1, 0); STG_B(0, 0, 0); STG_B(0, 1, 0);
  STG_A(65536, 0, 1); STG_A(65536, 1, 1); STG_B(65536, 0, 1);
  VMW(6);                    // tile0 landed; tile1's 6 loads in flight
  BARSB;
  LDAH(a0f, 0, 0);           // a0 = A0(0)
  LDBH(b0f, 0, 0);           // b0 = B0(0)   (drained by P0(0)'s LGW(8))

  // Stagers: S2 true for ALL tiles 0..13 (tile T stages tile T+2; tiles 2..15
  // each staged exactly once). [R4 bug: S2 was (T<13), skipping tile13 ->
  // tile15's A_lo/A_hi/B_lo never staged -> stale-data absmax 2.8e-2.]
  #pragma unroll 1
  for (int kt = 0; kt < 14; kt += 2) {
    TILE(kt,     0,     65536, true, true, true, 4, 8);
    TILE(kt + 1, 65536, 0,     true, true, true, 4, 8);
  }
  TILE(14, 0,     65536, true,  false, true,  4, 8);
  TILE(15, 65536, 0,     false, false, false, 0, 0);

#undef STG_A
#undef STG_B
#undef LDAH
#undef LDBH
#undef QUAD
#undef TILE

  // epilogue: C/D layout col=lane&15, row=(lane>>4)*4+reg  [m89-verified]
  // acc[i][j]: rows i*16 (i=0..7), cols j*16 (j=0..3) within wave's 128x64.
  // T15 P3: LGW(0) + final barrier -> all LDS traffic drained before reuse.
  const int colb = ln & 15, rowb = (ln >> 4) * 4;

  if constexpr (MODE == 0) {
    const int region = yb >> 2;                 // 4 y-blocks per 1024 cols
    const int nl0 = (yb & 3) * 256;
    const float* bias = region == 0 ? b0 : (region == 1 ? b1 : b2);
    ushort_t* gout    = region == 0 ? o0 : (region == 1 ? o1 : o2);
    const bool act = region < 2;
    ushort_t* Cs = (ushort_t*)smem;             // 256x256 bf16, chunk-XOR swizzled, 128 KB
    #pragma unroll
    for (int j = 0; j < 4; ++j) {
      const int col = wn * 64 + j * 16 + colb;
      const float bv_ = bias[nl0 + col];
      #pragma unroll
      for (int i = 0; i < 8; ++i) {
        const int rb_ = wm * 128 + i * 16 + rowb;
        #pragma unroll
        for (int r = 0; r < 4; ++r) {
          float v = acc[i][j][r] + bv_;
          if (act) v = (v > 0.f) ? v + 1.f : __expf(v);   // elu(v)+1
          const int row = rb_ + r;
          const int ch = col >> 3;
          Cs[row * 256 + ((ch ^ (row & 31)) << 3) + (col & 7)] = f2bf(v);
        }
      }
    }
    __syncthreads();
    #pragma unroll
    for (int c = 0; c < 16; ++c) {
      const int idx = c * 512 + tid;
      const int row = idx >> 5, ch = idx & 31;
      short8 t = *(const short8*)&Cs[row * 256 + ((ch ^ (row & 31)) << 3)];
      *(short8*)&gout[(size_t)(m0 + row) * D_MODEL + nl0 + ch * 8] = t;
    }
  } else {
    float* Cf = (float*)smem;                   // 128x256 fp32 per half, chunk-swizzled, 128 KB
    #pragma unroll
    for (int h = 0; h < 2; ++h) {
      if (h) __syncthreads();
      if (wm == h) {
        #pragma unroll
        for (int j = 0; j < 4; ++j) {
          const int col = wn * 64 + j * 16 + colb;
          const float bv_ = b0[n0 + col];
          #pragma unroll
          for (int i = 0; i < 8; ++i) {
            const int rl = i * 16 + rowb;
            #pragma unroll
            for (int r = 0; r < 4; ++r) {
              const int row = rl + r;
              const int ch = col >> 2;
              Cf[row * 256 + ((ch ^ (row & 7)) << 2) + (col & 3)] = acc[i][j][r] + bv_;
            }
          }
        }
      }
      __syncthreads();
      #pragma unroll
      for (int c = 0; c < 16; ++c) {
        const int idx = c * 512 + tid;
        const int row = idx >> 6, ch = idx & 63;
        float4 t = *(const float4*)&Cf[row * 256 + ((ch ^ (row & 7)) << 2)];
        *(float4*)&outf[(size_t)(m0 + h * 128 + row) * D_MODEL + n0 + ch * 4] = t;
      }
    }
  }
#undef VMW_
#undef VMW
#undef LGW_
#undef LGW__
#undef LGW
#undef BARSB
}

// ---------------- kv partial: per (b,h,chunk,wave) 64x64 outer-product sum + ksum ----------------
__global__ __launch_bounds__(256) void k_kv_partial(const ushort_t* __restrict__ kmat,
                                                    const ushort_t* __restrict__ vmat,
                                                    float* __restrict__ part) {
  __shared__ __align__(16) ushort_t sbuf[4][2][2][512];  // [wave][parity][k/v][8rows*64]
  const int tid = threadIdx.x, ln = tid & 63, w = tid >> 6;
  const int wb = __builtin_amdgcn_readfirstlane(w);
  const int bh = blockIdx.y, chunk = blockIdx.x;
  const int b = bh >> 4, h = bh & 15;
  const size_t cbase = ((size_t)b * SEQ + chunk * 1024 + w * 256) * D_MODEL + h * 64;
  const ushort_t* gk = kmat + cbase + (size_t)(ln >> 3) * D_MODEL + (ln & 7) * 8;
  const ushort_t* gv = vmat + cbase + (size_t)(ln >> 3) * D_MODEL + (ln & 7) * 8;

  float acc[8][8];
  float ksum[8];
  #pragma unroll
  for (int i = 0; i < 8; i++) { ksum[i] = 0.f;
    #pragma unroll
    for (int j = 0; j < 8; j++) acc[i][j] = 0.f; }

  const int r8 = (ln >> 3) * 8, c8 = (ln & 7) * 8;
  gll16(gk, &sbuf[wb][0][0][0]);
  gll16(gv, &sbuf[wb][0][1][0]);
  gk += 8 * D_MODEL; gv += 8 * D_MODEL;

  for (int bt = 0; bt < 32; bt++) {
    const int p = bt & 1;
    if (bt < 31) {
      gll16(gk, &sbuf[wb][p ^ 1][0][0]);
      gll16(gv, &sbuf[wb][p ^ 1][1][0]);
      gk += 8 * D_MODEL; gv += 8 * D_MODEL;
      __builtin_amdgcn_s_waitcnt(0x0F72);  // vmcnt(2): current batch landed
    } else {
      __builtin_amdgcn_s_waitcnt(0x0F70);  // vmcnt(0)
    }
    #pragma unroll
    for (int s = 0; s < 8; s++) {
      short8 kk = *(const short8*)&sbuf[wb][p][0][s * 64 + r8];
      short8 vv = *(const short8*)&sbuf[wb][p][1][s * 64 + c8];
      float ka[8], va[8];
      #pragma unroll
      for (int i = 0; i < 8; i++) {
        ka[i] = __builtin_bit_cast(float, (uint32_t)(ushort_t)kk[i] << 16);
        va[i] = __builtin_bit_cast(float, (uint32_t)(ushort_t)vv[i] << 16);
      }
      #pragma unroll
      for (int i = 0; i < 8; i++) {
        ksum[i] += ka[i];
        #pragma unroll
        for (int j = 0; j < 8; j++) acc[i][j] += ka[i] * va[j];
      }
    }
  }
  float* p0 = part + ((size_t)bh * 32 + chunk * 4 + w) * 4160;
  #pragma unroll
  for (int i = 0; i < 8; i++)
    #pragma unroll
    for (int j = 0; j < 8; j++) p0[(r8 + i) * 64 + c8 + j] = acc[i][j];
  if ((ln & 7) == 0) {
    #pragma unroll
    for (int i = 0; i < 8; i++) p0[4096 + r8 + i] = ksum[i];
  }
}

// ---------------- reduce partials -> kvT bf16 [bh][65][64] (row m holds kv[.][m]; row 64 = ksum) ----------------
__global__ void k_kv_reduce(const float* __restrict__ part, ushort_t* __restrict__ kvt) {
  const int bh = blockIdx.x, tid = threadIdx.x;
  const float* p0 = part + (size_t)bh * 32 * 4160;
  for (int idx = tid; idx < 4160; idx += 256) {
    float s = 0.f;
    #pragma unroll 4
    for (int c = 0; c < 32; c++) s += p0[(size_t)c * 4160 + idx];
    ushort_t bf = f2bf(s);
    if (idx < 4096) { int d = idx >> 6, m = idx & 63; kvt[(size_t)bh * 4160 + m * 64 + d] = bf; }
    else            { kvt[(size_t)bh * 4160 + 4096 + (idx - 4096)] = bf; }
  }
}

// ---------------- attn: out = (q @ kv) / max(q . ksum, eps), bf16 out ----------------
__global__ __launch_bounds__(256) void k_attn(const ushort_t* __restrict__ qmat,
                                              const ushort_t* __restrict__ kvt,
                                              ushort_t* __restrict__ attn) {
  __shared__ __align__(16) ushort_t kvs[65 * 80];     // kvT rows stride 80
  __shared__ __align__(16) ushort_t qs[4][64 * 80];   // per-wave q tile, stride 80
  const int tid = threadIdx.x, ln = tid & 63, w = tid >> 6;
  const int bh = blockIdx.y, b = bh >> 4, h = bh & 15;

  for (int idx = tid; idx < 4160; idx += 256) {
    int m = idx >> 6, d = idx & 63;
    kvs[m * 80 + d] = kvt[(size_t)bh * 4160 + idx];
  }
  const size_t s0 = (size_t)b * SEQ + blockIdx.x * 256 + w * 64;
  #pragma unroll
  for (int c = 0; c < 8; c++) {
    int f = c * 64 + ln;
    int row = f >> 3, dg = (f & 7) * 8;
    short8 t = *(const short8*)&qmat[(s0 + row) * D_MODEL + h * 64 + dg];
    *(short8*)&qs[w][row * 80 + dg] = t;
  }
  __syncthreads();

  const int ar = ln & 15, aq = (ln >> 4) * 8;
  f32x4 acc[4][4], nacc[4];
  #pragma unroll
  for (int i = 0; i < 4; i++) { nacc[i] = (f32x4){0.f, 0.f, 0.f, 0.f};
    #pragma unroll
    for (int j = 0; j < 4; j++) acc[i][j] = (f32x4){0.f, 0.f, 0.f, 0.f}; }

  #pragma unroll
  for (int kk = 0; kk < 2; kk++) {
    const int ko = kk * 32 + aq;
    bf16x8 a[4], bb[4], bn;
    #pragma unroll
    for (int i = 0; i < 4; i++) a[i] = *(const bf16x8*)&qs[w][(i * 16 + ar) * 80 + ko];
    #pragma unroll
    for (int j = 0; j < 4; j++) bb[j] = *(const bf16x8*)&kvs[(j * 16 + ar) * 80 + ko];
    bn = *(const bf16x8*)&kvs[64 * 80 + ko];
    #pragma unroll
    for (int i = 0; i < 4; i++) {
      #pragma unroll
      for (int j = 0; j < 4; j++)
        acc[i][j] = __builtin_amdgcn_mfma_f32_16x16x32_bf16(a[i], bb[j], acc[i][j], 0, 0, 0);
      nacc[i] = __builtin_amdgcn_mfma_f32_16x16x32_bf16(a[i], bn, nacc[i], 0, 0, 0);
    }
  }

  const int colb = ln & 15, rowb = (ln >> 4) * 4;
  #pragma unroll
  for (int i = 0; i < 4; i++) {
    #pragma unroll
    for (int r = 0; r < 4; r++) {
      const int row = i * 16 + rowb + r;
      float nm = fmaxf(nacc[i][r], 1e-6f);
      float inv = 1.0f / nm;
      const size_t grow = s0 + row;
      #pragma unroll
      for (int j = 0; j < 4; j++) {
        float v = acc[i][j][r] * inv;
        attn[grow * D_MODEL + h * 64 + j * 16 + colb] = f2bf(v);
      }
    }
  }
}

extern "C" void kernel_launch(void* const* d_in, const int* in_sizes, int n_in,
                              void* d_out, int out_size, void* d_ws, size_t ws_size,
                              hipStream_t stream) {
  const float* x  = (const float*)d_in[0];
  const float* Wq = (const float*)d_in[1];
  const float* bq = (const float*)d_in[2];
  const float* Wk = (const float*)d_in[3];
  const float* bk = (const float*)d_in[4];
  const float* Wv = (const float*)d_in[5];
  const float* bv = (const float*)d_in[6];
  const float* Wo = (const float*)d_in[7];
  const float* bo = (const float*)d_in[8];
  float* out = (float*)d_out;

  const int M = in_sizes[0] / D_MODEL;       // 32768
  const int B = M / SEQ;                     // 4
  const int BH = B * 16;                     // 64

  char* ws = (char*)d_ws;
  size_t off = 0;
  auto alloc = [&](size_t bytes) { char* p = ws + off; off += (bytes + 255) & ~(size_t)255; return p; };
  const size_t mb = (size_t)M * D_MODEL * 2;               // 64 MB per bf16 matrix
  ushort_t* xb    = (ushort_t*)alloc(mb);
  ushort_t* qb    = (ushort_t*)alloc(mb);
  ushort_t* kb    = (ushort_t*)alloc(mb);
  ushort_t* vb    = (ushort_t*)alloc(mb);
  ushort_t* attnb = (ushort_t*)alloc(mb);
  ushort_t* wqkvt = (ushort_t*)alloc((size_t)3 * D_MODEL * D_MODEL * 2);
  ushort_t* wot   = (ushort_t*)alloc((size_t)D_MODEL * D_MODEL * 2);
  ushort_t* kvt   = (ushort_t*)alloc((size_t)BH * 4160 * 2);
  float*    part  = (float*)   alloc((size_t)BH * 32 * 4160 * 4);
  (void)ws_size; (void)n_in; (void)out_size;

  const int n = M * D_MODEL;
  k_convert_x<<<n / (256 * 8), 256, 0, stream>>>(x, xb, n);
  k_transpose_w<<<dim3(16, 16, 4), 256, 0, stream>>>(Wq, Wk, Wv, Wo, wqkvt, wot);

  // Fused QKV: N = 3072, 256x256 tiles, 1D grid decoded N-fastest + XCD swizzle
  k_gemm<0, 12><<<(M / 256) * 12, 512, 0, stream>>>(xb, wqkvt, bq, bk, bv, qb, kb, vb, nullptr);

  k_kv_partial<<<dim3(8, BH), 256, 0, stream>>>(kb, vb, part);
  k_kv_reduce<<<BH, 256, 0, stream>>>(part, kvt);
  k_attn<<<dim3(SEQ / 256, BH), 256, 0, stream>>>(qb, kvt, attnb);

  // Output projection: fp32 out
  k_gemm<2, 4><<<(M / 256) * 4, 512, 0, stream>>>(attnb, wot, bo, nullptr, nullptr, nullptr, nullptr, nullptr, out);
}

// Round 6
// 681.612 us; speedup vs baseline: 1.1852x; 1.1852x over previous
//
#include <hip/hip_runtime.h>
#include <cstdint>
#include <cstddef>

#define D_MODEL 1024
#define SEQ 8192

typedef __bf16  bf16x8 __attribute__((ext_vector_type(8)));
typedef short   short8 __attribute__((ext_vector_type(8)));
typedef float   f32x4  __attribute__((ext_vector_type(4)));
typedef unsigned short ushort_t;

__device__ __forceinline__ ushort_t f2bf(float f) {
  uint32_t u = __builtin_bit_cast(uint32_t, f);
  u += 0x7FFFu + ((u >> 16) & 1u);          // round-to-nearest-even
  return (ushort_t)(u >> 16);
}
// async global->LDS, 16B per lane. LDS dest is wave-uniform base + lane*16.
__device__ __forceinline__ void gll16(const void* g, void* l) {
  __builtin_amdgcn_global_load_lds(
      (const __attribute__((address_space(1))) void*)g,
      (__attribute__((address_space(3))) void*)l, 16, 0, 0);
}
// stage one 128x64 bf16 half-tile (16 KB): 2 gll16 per lane, 8 waves cover 128 rows.
__device__ __forceinline__ void stage_half(const ushort_t* g, char* l0) {
  gll16(g, l0);                       // rows  0..63 of half
  gll16(g + 65536, l0 + 8192);        // rows 64..127 of half (+64*1024 elems)
}

// ---------------- fp32 -> bf16 conversion of x ----------------
__global__ void k_convert_x(const float* __restrict__ x, ushort_t* __restrict__ xb, int n) {
  int i = (blockIdx.x * 256 + threadIdx.x) * 8;
  if (i >= n) return;
  float4 v0 = *(const float4*)(x + i);
  float4 v1 = *(const float4*)(x + i + 4);
  ushort_t o[8] = { f2bf(v0.x), f2bf(v0.y), f2bf(v0.z), f2bf(v0.w),
                    f2bf(v1.x), f2bf(v1.y), f2bf(v1.z), f2bf(v1.w) };
  *(short8*)(xb + i) = *(const short8*)o;
}

// ---------------- W (k,n) fp32 -> Wt (n,k) bf16; z<3 -> fused qkv buffer ----------------
__global__ void k_transpose_w(const float* W0, const float* W1, const float* W2, const float* W3,
                              ushort_t* Tqkv, ushort_t* To) {
  const float* src; ushort_t* dst;
  switch (blockIdx.z) {
    case 0: src = W0; dst = Tqkv; break;
    case 1: src = W1; dst = Tqkv + (size_t)1024 * 1024; break;
    case 2: src = W2; dst = Tqkv + (size_t)2048 * 1024; break;
    default: src = W3; dst = To; break;
  }
  __shared__ float tile[64][65];
  int tx = threadIdx.x;
  int c = tx & 63, r0 = tx >> 6;
  int bx = blockIdx.x * 64, by = blockIdx.y * 64;
  #pragma unroll
  for (int i = 0; i < 16; i++) {
    int r = i * 4 + r0;
    tile[r][c] = src[(size_t)(by + r) * D_MODEL + bx + c];
  }
  __syncthreads();
  #pragma unroll
  for (int i = 0; i < 16; i++) {
    int r = i * 4 + r0;
    dst[(size_t)(bx + r) * D_MODEL + by + c] = f2bf(tile[c][r]);
  }
}

// ---------------- 256x256-tile bf16 GEMM: m201-port 4-phase schedule ----------------
// C = A(M,K) * Bt(N,K)^T + bias. BK=64, 8 waves (2Mx4N), LDS 128KB dbuf, 1 block/CU.
// Faithful port of the verified 8-phase template (m201, 1563 TF @4k): per K-tile,
// 4 phases = C-quadrants Q00,Q01,Q11,Q10. Each phase:
//   {ds_read subtile (12/4/8/0) ; stage ; [lgkm(8) cap if 12 reads] ; barrier ;
//    lgkmcnt(0)+sched_barrier ; setprio(1) ; 16 MFMA ; setprio(0) ; [vmcnt] ; barrier}
// Registers: one reused A-half (32 VGPR) + B0,B1 halves (16+16); B0 lives to ph3.
// Staging: tile T stages T+2 into the CURRENT buffer at region-death points:
//   B_lo+B_hi @ph2-top (B(T) reads drained at ph1's lgkm(0), one barrier earlier)
//   A_lo+A_hi @ph3-top (A(T) reads drained at ph2's lgkm(0))
// One vmcnt(8)/tile at ph3 (T+1's 8 stage-ops drained, T+2's 8 in flight);
// vmcnt(0) at tile14 only. T1 XCD swizzle, T2 chunk-XOR swizzle, T5 setprio.
// MODE 0: fused QKV (N=3072): region 0/1 -> elu+1 -> o0/o1; region 2 -> o2. bf16 out.
// MODE 2: fp32 out (+bias), single output.
template<int MODE, int NY>
__global__ __launch_bounds__(512, 2) void k_gemm(const ushort_t* __restrict__ A,
                                                 const ushort_t* __restrict__ Bt,
                                                 const float* __restrict__ b0,
                                                 const float* __restrict__ b1,
                                                 const float* __restrict__ b2,
                                                 ushort_t* __restrict__ o0,
                                                 ushort_t* __restrict__ o1,
                                                 ushort_t* __restrict__ o2,
                                                 float* __restrict__ outf) {
  __shared__ __align__(16) char smem[131072];   // 2 x (A 32KB + B 32KB) dbuf; epilogue reuses

  const int nwg = gridDim.x;
  const int bid0 = blockIdx.x;
  const int bid = (bid0 & 7) * (nwg >> 3) + (bid0 >> 3);   // XCD-aware, bijective (nwg%8==0)
  const int xb = bid / NY, yb = bid % NY;                  // N-fastest: A-panel L2 reuse
  const int m0 = xb * 256, n0 = yb * 256;

  const int tid = threadIdx.x;
  const int ln = tid & 63;
  const int w  = tid >> 6;
  const int wb = __builtin_amdgcn_readfirstlane(w);
  const int wm = wb >> 2, wn = wb & 3;          // 2x4 wave grid; per-wave C = 128x64

  // --- staging: thread's (row,chunk) slot; global chunk pre-swizzled (c ^= row&7) ---
  const int srow = wb * 8 + (ln >> 3);                       // row in half-tile
  const int schk = ((ln & 7) ^ ((ln >> 3) & 7)) * 8;         // swizzled source chunk (elems)
  const ushort_t* gA = A  + (size_t)(m0 + srow) * D_MODEL + schk;
  const ushort_t* gB = Bt + (size_t)(n0 + srow) * D_MODEL + schk;

#define STG_A(BASE, H, T) stage_half(gA + (size_t)(T) * 64 + (size_t)(H) * 131072, smem + (BASE) + (H) * 16384 + wb * 1024)
#define STG_B(BASE, H, T) stage_half(gB + (size_t)(T) * 64 + (size_t)(H) * 131072, smem + (BASE) + 32768 + (H) * 16384 + wb * 1024)

#define VMW_(N) asm volatile("s_waitcnt vmcnt(" #N ")" ::: "memory")
#define VMW(N)  VMW_(N)
#define LGWC_(N) asm volatile("s_waitcnt lgkmcnt(" #N ")" ::: "memory")
#define LGW0 do { LGWC_(0); __builtin_amdgcn_sched_barrier(0); } while (0)
#define BARSB { __builtin_amdgcn_s_barrier(); __builtin_amdgcn_sched_barrier(0); }

  f32x4 acc[8][4];
  #pragma unroll
  for (int i = 0; i < 8; i++)
    #pragma unroll
    for (int j = 0; j < 4; j++) acc[i][j] = (f32x4){0.f, 0.f, 0.f, 0.f};
  bf16x8 af[4][2];                  // A-half frags (64 rows x 64 K), reused mh=0 -> mh=1
  bf16x8 bf0[2][2], bf1[2][2];      // B-half frags (32 cols x 64 K); bf0 lives ph0..ph3

  const int ar  = ln & 15;
  const int cw0 = (((ln >> 4)    ) ^ (ln & 7)) << 4;         // swizzled 16B chunk offs, ksub0
  const int cw1 = (((ln >> 4) + 4) ^ (ln & 7)) << 4;         // ksub1

// A-half MH (64 rows: wm*128 + MH*64): 8 ds_read_b128
#define LDAH(BASE, MH) { _Pragma("unroll") for (int m_ = 0; m_ < 4; ++m_) { \
    const char* p_ = smem + (BASE) + ((wm * 128 + (MH) * 64 + m_ * 16 + ar) << 7); \
    af[m_][0] = *(const bf16x8*)(p_ + cw0); af[m_][1] = *(const bf16x8*)(p_ + cw1); } }
// B-half NH (32 cols: wn*64 + NH*32): 4 ds_read_b128
#define LDBH(DST, BASE, NH) { _Pragma("unroll") for (int j_ = 0; j_ < 2; ++j_) { \
    const char* p_ = smem + (BASE) + 32768 + ((wn * 64 + (NH) * 32 + j_ * 16 + ar) << 7); \
    DST[j_][0] = *(const bf16x8*)(p_ + cw0); DST[j_][1] = *(const bf16x8*)(p_ + cw1); } }
// quadrant (MH,NH): 16 MFMA into acc[MH*4+m_][NH*2+j_]
#define QUAD(MH, NH, BF) { _Pragma("unroll") for (int m_ = 0; m_ < 4; ++m_) \
    _Pragma("unroll") for (int j_ = 0; j_ < 2; ++j_) { \
      acc[(MH)*4+m_][(NH)*2+j_] = __builtin_amdgcn_mfma_f32_16x16x32_bf16(af[m_][0], BF[j_][0], acc[(MH)*4+m_][(NH)*2+j_], 0, 0, 0); \
      acc[(MH)*4+m_][(NH)*2+j_] = __builtin_amdgcn_mfma_f32_16x16x32_bf16(af[m_][1], BF[j_][1], acc[(MH)*4+m_][(NH)*2+j_], 0, 0, 0); } }

  // One K-tile. CUR: LDS base of tile T's buffer (compile-time).
  // S2: stage T+2 (tiles 0..13). VM: 0 -> vmcnt(8), 1 -> vmcnt(0) [tile14], 2 -> none.
#define TILE(T, CUR, S2, VM) { \
    /* ph0: Q00.  reads A-half0 (8) + B-half0 (4) = 12 */ \
    LDAH(CUR, 0); \
    LDBH(bf0, CUR, 0); \
    LGWC_(8); \
    BARSB; \
    LGW0; \
    __builtin_amdgcn_s_setprio(1); QUAD(0, 0, bf0); __builtin_amdgcn_s_setprio(0); \
    BARSB; \
    /* ph1: Q01.  reads B-half1 (4).  B(T) regions dead after this lgkm(0). */ \
    LDBH(bf1, CUR, 1); \
    BARSB; \
    LGW0; \
    __builtin_amdgcn_s_setprio(1); QUAD(0, 1, bf1); __builtin_amdgcn_s_setprio(0); \
    BARSB; \
    /* ph2: Q11.  reads A-half1 (8, reuse af); stage B(T+2) -> CUR B-region. */ \
    LDAH(CUR, 1); \
    if (S2) { STG_B(CUR, 0, (T) + 2); STG_B(CUR, 1, (T) + 2); } \
    BARSB; \
    LGW0; \
    __builtin_amdgcn_s_setprio(1); QUAD(1, 1, bf1); __builtin_amdgcn_s_setprio(0); \
    BARSB; \
    /* ph3: Q10.  no reads; stage A(T+2) -> CUR A-region (A(T) dead after ph2). */ \
    if (S2) { STG_A(CUR, 0, (T) + 2); STG_A(CUR, 1, (T) + 2); } \
    BARSB; \
    __builtin_amdgcn_s_setprio(1); QUAD(1, 0, bf0); __builtin_amdgcn_s_setprio(0); \
    if ((VM) == 0) VMW(8);       /* T+1's stages drained; T+2's 8 in flight */ \
    else if ((VM) == 1) VMW(0);  /* tile14: drain T15 fully */ \
    BARSB; \
  }

  // prologue: stage tile0 + tile1 fully (16 ops); vmcnt(8) -> tile0 landed, tile1 in flight.
  STG_A(0, 0, 0); STG_A(0, 1, 0); STG_B(0, 0, 0); STG_B(0, 1, 0);
  STG_A(65536, 0, 1); STG_A(65536, 1, 1); STG_B(65536, 0, 1); STG_B(65536, 1, 1);
  VMW(8);
  BARSB;

  #pragma unroll 1
  for (int kt = 0; kt < 14; kt += 2) {
    TILE(kt,     0,     true, 0);
    TILE(kt + 1, 65536, true, 0);
  }
  TILE(14, 0,     false, 1);
  TILE(15, 65536, false, 2);

#undef STG_A
#undef STG_B
#undef LDAH
#undef LDBH
#undef QUAD
#undef TILE

  // epilogue: C/D layout col=lane&15, row=(lane>>4)*4+reg  [m89-verified]
  // acc[i][j]: rows i*16 (i=0..7), cols j*16 (j=0..3) within wave's 128x64.
  // tile15 ph2's LGW0 drained all reads; no stages in flight; ph3-end barrier done.
  const int colb = ln & 15, rowb = (ln >> 4) * 4;

  if constexpr (MODE == 0) {
    const int region = yb >> 2;                 // 4 y-blocks per 1024 cols
    const int nl0 = (yb & 3) * 256;
    const float* bias = region == 0 ? b0 : (region == 1 ? b1 : b2);
    ushort_t* gout    = region == 0 ? o0 : (region == 1 ? o1 : o2);
    const bool act = region < 2;
    ushort_t* Cs = (ushort_t*)smem;             // 256x256 bf16, chunk-XOR swizzled, 128 KB
    #pragma unroll
    for (int j = 0; j < 4; ++j) {
      const int col = wn * 64 + j * 16 + colb;
      const float bv_ = bias[nl0 + col];
      #pragma unroll
      for (int i = 0; i < 8; ++i) {
        const int rb_ = wm * 128 + i * 16 + rowb;
        #pragma unroll
        for (int r = 0; r < 4; ++r) {
          float v = acc[i][j][r] + bv_;
          if (act) v = (v > 0.f) ? v + 1.f : __expf(v);   // elu(v)+1
          const int row = rb_ + r;
          const int ch = col >> 3;
          Cs[row * 256 + ((ch ^ (row & 31)) << 3) + (col & 7)] = f2bf(v);
        }
      }
    }
    __syncthreads();
    #pragma unroll
    for (int c = 0; c < 16; ++c) {
      const int idx = c * 512 + tid;
      const int row = idx >> 5, ch = idx & 31;
      short8 t = *(const short8*)&Cs[row * 256 + ((ch ^ (row & 31)) << 3)];
      *(short8*)&gout[(size_t)(m0 + row) * D_MODEL + nl0 + ch * 8] = t;
    }
  } else {
    float* Cf = (float*)smem;                   // 128x256 fp32 per half, chunk-swizzled, 128 KB
    #pragma unroll
    for (int h = 0; h < 2; ++h) {
      if (h) __syncthreads();
      if (wm == h) {
        #pragma unroll
        for (int j = 0; j < 4; ++j) {
          const int col = wn * 64 + j * 16 + colb;
          const float bv_ = b0[n0 + col];
          #pragma unroll
          for (int i = 0; i < 8; ++i) {
            const int rl = i * 16 + rowb;
            #pragma unroll
            for (int r = 0; r < 4; ++r) {
              const int row = rl + r;
              const int ch = col >> 2;
              Cf[row * 256 + ((ch ^ (row & 7)) << 2) + (col & 3)] = acc[i][j][r] + bv_;
            }
          }
        }
      }
      __syncthreads();
      #pragma unroll
      for (int c = 0; c < 16; ++c) {
        const int idx = c * 512 + tid;
        const int row = idx >> 6, ch = idx & 63;
        float4 t = *(const float4*)&Cf[row * 256 + ((ch ^ (row & 7)) << 2)];
        *(float4*)&outf[(size_t)(m0 + h * 128 + row) * D_MODEL + n0 + ch * 4] = t;
      }
    }
  }
#undef VMW_
#undef VMW
#undef LGWC_
#undef LGW0
#undef BARSB
}

// ---------------- kv partial: per (b,h,chunk,wave) 64x64 outer-product sum + ksum ----------------
__global__ __launch_bounds__(256) void k_kv_partial(const ushort_t* __restrict__ kmat,
                                                    const ushort_t* __restrict__ vmat,
                                                    float* __restrict__ part) {
  __shared__ __align__(16) ushort_t sbuf[4][2][2][512];  // [wave][parity][k/v][8rows*64]
  const int tid = threadIdx.x, ln = tid & 63, w = tid >> 6;
  const int wb = __builtin_amdgcn_readfirstlane(w);
  const int bh = blockIdx.y, chunk = blockIdx.x;
  const int b = bh >> 4, h = bh & 15;
  const size_t cbase = ((size_t)b * SEQ + chunk * 1024 + w * 256) * D_MODEL + h * 64;
  const ushort_t* gk = kmat + cbase + (size_t)(ln >> 3) * D_MODEL + (ln & 7) * 8;
  const ushort_t* gv = vmat + cbase + (size_t)(ln >> 3) * D_MODEL + (ln & 7) * 8;

  float acc[8][8];
  float ksum[8];
  #pragma unroll
  for (int i = 0; i < 8; i++) { ksum[i] = 0.f;
    #pragma unroll
    for (int j = 0; j < 8; j++) acc[i][j] = 0.f; }

  const int r8 = (ln >> 3) * 8, c8 = (ln & 7) * 8;
  gll16(gk, &sbuf[wb][0][0][0]);
  gll16(gv, &sbuf[wb][0][1][0]);
  gk += 8 * D_MODEL; gv += 8 * D_MODEL;

  for (int bt = 0; bt < 32; bt++) {
    const int p = bt & 1;
    if (bt < 31) {
      gll16(gk, &sbuf[wb][p ^ 1][0][0]);
      gll16(gv, &sbuf[wb][p ^ 1][1][0]);
      gk += 8 * D_MODEL; gv += 8 * D_MODEL;
      __builtin_amdgcn_s_waitcnt(0x0F72);  // vmcnt(2): current batch landed
    } else {
      __builtin_amdgcn_s_waitcnt(0x0F70);  // vmcnt(0)
    }
    #pragma unroll
    for (int s = 0; s < 8; s++) {
      short8 kk = *(const short8*)&sbuf[wb][p][0][s * 64 + r8];
      short8 vv = *(const short8*)&sbuf[wb][p][1][s * 64 + c8];
      float ka[8], va[8];
      #pragma unroll
      for (int i = 0; i < 8; i++) {
        ka[i] = __builtin_bit_cast(float, (uint32_t)(ushort_t)kk[i] << 16);
        va[i] = __builtin_bit_cast(float, (uint32_t)(ushort_t)vv[i] << 16);
      }
      #pragma unroll
      for (int i = 0; i < 8; i++) {
        ksum[i] += ka[i];
        #pragma unroll
        for (int j = 0; j < 8; j++) acc[i][j] += ka[i] * va[j];
      }
    }
  }
  float* p0 = part + ((size_t)bh * 32 + chunk * 4 + w) * 4160;
  #pragma unroll
  for (int i = 0; i < 8; i++)
    #pragma unroll
    for (int j = 0; j < 8; j++) p0[(r8 + i) * 64 + c8 + j] = acc[i][j];
  if ((ln & 7) == 0) {
    #pragma unroll
    for (int i = 0; i < 8; i++) p0[4096 + r8 + i] = ksum[i];
  }
}

// ---------------- reduce partials -> kvT bf16 [bh][65][64] (row m holds kv[.][m]; row 64 = ksum) ----------------
__global__ void k_kv_reduce(const float* __restrict__ part, ushort_t* __restrict__ kvt) {
  const int bh = blockIdx.x, tid = threadIdx.x;
  const float* p0 = part + (size_t)bh * 32 * 4160;
  for (int idx = tid; idx < 4160; idx += 256) {
    float s = 0.f;
    #pragma unroll 4
    for (int c = 0; c < 32; c++) s += p0[(size_t)c * 4160 + idx];
    ushort_t bf = f2bf(s);
    if (idx < 4096) { int d = idx >> 6, m = idx & 63; kvt[(size_t)bh * 4160 + m * 64 + d] = bf; }
    else            { kvt[(size_t)bh * 4160 + 4096 + (idx - 4096)] = bf; }
  }
}

// ---------------- attn: out = (q @ kv) / max(q . ksum, eps), bf16 out ----------------
__global__ __launch_bounds__(256) void k_attn(const ushort_t* __restrict__ qmat,
                                              const ushort_t* __restrict__ kvt,
                                              ushort_t* __restrict__ attn) {
  __shared__ __align__(16) ushort_t kvs[65 * 80];     // kvT rows stride 80
  __shared__ __align__(16) ushort_t qs[4][64 * 80];   // per-wave q tile, stride 80
  const int tid = threadIdx.x, ln = tid & 63, w = tid >> 6;
  const int bh = blockIdx.y, b = bh >> 4, h = bh & 15;

  for (int idx = tid; idx < 4160; idx += 256) {
    int m = idx >> 6, d = idx & 63;
    kvs[m * 80 + d] = kvt[(size_t)bh * 4160 + idx];
  }
  const size_t s0 = (size_t)b * SEQ + blockIdx.x * 256 + w * 64;
  #pragma unroll
  for (int c = 0; c < 8; c++) {
    int f = c * 64 + ln;
    int row = f >> 3, dg = (f & 7) * 8;
    short8 t = *(const short8*)&qmat[(s0 + row) * D_MODEL + h * 64 + dg];
    *(short8*)&qs[w][row * 80 + dg] = t;
  }
  __syncthreads();

  const int ar = ln & 15, aq = (ln >> 4) * 8;
  f32x4 acc[4][4], nacc[4];
  #pragma unroll
  for (int i = 0; i < 4; i++) { nacc[i] = (f32x4){0.f, 0.f, 0.f, 0.f};
    #pragma unroll
    for (int j = 0; j < 4; j++) acc[i][j] = (f32x4){0.f, 0.f, 0.f, 0.f}; }

  #pragma unroll
  for (int kk = 0; kk < 2; kk++) {
    const int ko = kk * 32 + aq;
    bf16x8 a[4], bb[4], bn;
    #pragma unroll
    for (int i = 0; i < 4; i++) a[i] = *(const bf16x8*)&qs[w][(i * 16 + ar) * 80 + ko];
    #pragma unroll
    for (int j = 0; j < 4; j++) bb[j] = *(const bf16x8*)&kvs[(j * 16 + ar) * 80 + ko];
    bn = *(const bf16x8*)&kvs[64 * 80 + ko];
    #pragma unroll
    for (int i = 0; i < 4; i++) {
      #pragma unroll
      for (int j = 0; j < 4; j++)
        acc[i][j] = __builtin_amdgcn_mfma_f32_16x16x32_bf16(a[i], bb[j], acc[i][j], 0, 0, 0);
      nacc[i] = __builtin_amdgcn_mfma_f32_16x16x32_bf16(a[i], bn, nacc[i], 0, 0, 0);
    }
  }

  const int colb = ln & 15, rowb = (ln >> 4) * 4;
  #pragma unroll
  for (int i = 0; i < 4; i++) {
    #pragma unroll
    for (int r = 0; r < 4; r++) {
      const int row = i * 16 + rowb + r;
      float nm = fmaxf(nacc[i][r], 1e-6f);
      float inv = 1.0f / nm;
      const size_t grow = s0 + row;
      #pragma unroll
      for (int j = 0; j < 4; j++) {
        float v = acc[i][j][r] * inv;
        attn[grow * D_MODEL + h * 64 + j * 16 + colb] = f2bf(v);
      }
    }
  }
}

extern "C" void kernel_launch(void* const* d_in, const int* in_sizes, int n_in,
                              void* d_out, int out_size, void* d_ws, size_t ws_size,
                              hipStream_t stream) {
  const float* x  = (const float*)d_in[0];
  const float* Wq = (const float*)d_in[1];
  const float* bq = (const float*)d_in[2];
  const float* Wk = (const float*)d_in[3];
  const float* bk = (const float*)d_in[4];
  const float* Wv = (const float*)d_in[5];
  const float* bv = (const float*)d_in[6];
  const float* Wo = (const float*)d_in[7];
  const float* bo = (const float*)d_in[8];
  float* out = (float*)d_out;

  const int M = in_sizes[0] / D_MODEL;       // 32768
  const int B = M / SEQ;                     // 4
  const int BH = B * 16;                     // 64

  char* ws = (char*)d_ws;
  size_t off = 0;
  auto alloc = [&](size_t bytes) { char* p = ws + off; off += (bytes + 255) & ~(size_t)255; return p; };
  const size_t mb = (size_t)M * D_MODEL * 2;               // 64 MB per bf16 matrix
  ushort_t* xb    = (ushort_t*)alloc(mb);
  ushort_t* qb    = (ushort_t*)alloc(mb);
  ushort_t* kb    = (ushort_t*)alloc(mb);
  ushort_t* vb    = (ushort_t*)alloc(mb);
  ushort_t* attnb = (ushort_t*)alloc(mb);
  ushort_t* wqkvt = (ushort_t*)alloc((size_t)3 * D_MODEL * D_MODEL * 2);
  ushort_t* wot   = (ushort_t*)alloc((size_t)D_MODEL * D_MODEL * 2);
  ushort_t* kvt   = (ushort_t*)alloc((size_t)BH * 4160 * 2);
  float*    part  = (float*)   alloc((size_t)BH * 32 * 4160 * 4);
  (void)ws_size; (void)n_in; (void)out_size;

  const int n = M * D_MODEL;
  k_convert_x<<<n / (256 * 8), 256, 0, stream>>>(x, xb, n);
  k_transpose_w<<<dim3(16, 16, 4), 256, 0, stream>>>(Wq, Wk, Wv, Wo, wqkvt, wot);

  // Fused QKV: N = 3072, 256x256 tiles, 1D grid decoded N-fastest + XCD swizzle
  k_gemm<0, 12><<<(M / 256) * 12, 512, 0, stream>>>(xb, wqkvt, bq, bk, bv, qb, kb, vb, nullptr);

  k_kv_partial<<<dim3(8, BH), 256, 0, stream>>>(kb, vb, part);
  k_kv_reduce<<<BH, 256, 0, stream>>>(part, kvt);
  k_attn<<<dim3(SEQ / 256, BH), 256, 0, stream>>>(qb, kvt, attnb);

  // Output projection: fp32 out
  k_gemm<2, 4><<<(M / 256) * 4, 512, 0, stream>>>(attnb, wot, bo, nullptr, nullptr, nullptr, nullptr, nullptr, out);
}